// Round 3
// baseline (150.198 us; speedup 1.0000x reference)
//
#include <hip/hip_runtime.h>
#include <hip/hip_bf16.h>

#define BD 4096
#define ID 1024
#define FD 2048

typedef __bf16 v8bf __attribute__((ext_vector_type(8)));
typedef float  v4f  __attribute__((ext_vector_type(4)));

struct alignas(8) bf4 { __hip_bfloat16 x, y, z, w; };

__device__ inline __hip_bfloat16 bf(float f) { return __float2bfloat16(f); }
__device__ inline float sig(float x) { return 1.f / (1.f + expf(-x)); }

// ---------- init: zero accumulators ----------
__global__ void k_init(float* scal, float* tau_raw, float* dec_raw) {
  int i = blockIdx.x * blockDim.x + threadIdx.x;
  if (i < 4) scal[i] = 0.f;
  if (i < FD) { tau_raw[i] = 0.f; dec_raw[i] = 0.f; }
}

// ---------- per-feature quantum state ----------
__global__ void k_prep_q(const float* ar, const float* ai, const float* ph,
                         const int* tstep, float* qs, float* pamp) {
  int j = blockIdx.x * 256 + threadIdx.x;
  if (j >= FD) return;
  float t = (float)tstep[0];
  float4 a = ((const float4*)ar)[j];
  float4 b = ((const float4*)ai)[j];
  float4 p = ((const float4*)ph)[j];
  float sr = 0.f, si = 0.f, pm = 0.f;
  {
    float c, s, rc, ic;
    c = cosf(p.x + 0.1f * t); s = sinf(p.x + 0.1f * t);
    rc = a.x * c; ic = b.x * s; sr += rc; si += ic; pm += rc * rc + ic * ic;
    c = cosf(p.y + 0.1f * t); s = sinf(p.y + 0.1f * t);
    rc = a.y * c; ic = b.y * s; sr += rc; si += ic; pm += rc * rc + ic * ic;
    c = cosf(p.z + 0.1f * t); s = sinf(p.z + 0.1f * t);
    rc = a.z * c; ic = b.z * s; sr += rc; si += ic; pm += rc * rc + ic * ic;
    c = cosf(p.w + 0.1f * t); s = sinf(p.w + 0.1f * t);
    rc = a.w * c; ic = b.w * s; sr += rc; si += ic; pm += rc * rc + ic * ic;
  }
  qs[j] = sr * expf(-si * si);
  pamp[j] = 0.25f * pm;
}

// ---------- f32 -> bf16 cast (4 elems/thread) ----------
__global__ void k_cast(const float* src, __hip_bfloat16* dst, int n4) {
  int i = blockIdx.x * blockDim.x + threadIdx.x;
  if (i >= n4) return;
  float4 v = ((const float4*)src)[i];
  bf4 o{bf(v.x), bf(v.y), bf(v.z), bf(v.w)};
  ((bf4*)dst)[i] = o;
}

// ---------- transpose + cast (+ optional M = P + E*corr[col]) ----------
// src [R][C] f32 -> dst [C][R] bf16
__global__ void k_tcast(const float* src, const float* src2, const float* corr,
                        __hip_bfloat16* dst, int R, int C, int useM) {
  __shared__ float t[32][33];
  int tx = threadIdx.x, ty = threadIdx.y;   // block (32,8)
  int x = blockIdx.x * 32 + tx;             // src col
  int yb = blockIdx.y * 32;                 // src row base
  float cr = useM ? corr[x] : 0.f;
#pragma unroll
  for (int j = 0; j < 4; j++) {
    int y = yb + ty + j * 8;
    float v = src[(size_t)y * C + x];
    if (useM) v += src2[(size_t)y * C + x] * cr;
    t[ty + j * 8][tx] = v;
  }
  __syncthreads();
#pragma unroll
  for (int j = 0; j < 4; j++) {
    int orow = blockIdx.x * 32 + ty + j * 8;  // = src col
    int ocol = yb + tx;                       // = src row
    dst[(size_t)orow * R + ocol] = bf(t[tx][ty + j * 8]);
  }
}

// ---------- split-K matvec: raw[j] += sum_i qs[i] * W[i][j] ----------
__global__ void k_matvec(const float* qs, const float* Wt, const float* Wd,
                         float* tau_raw, float* dec_raw) {
  int j = blockIdx.x * 256 + threadIdx.x;     // grid.x = 8
  int i0 = blockIdx.y * 128;                  // grid.y = 16
  const float* W = blockIdx.z ? Wd : Wt;      // grid.z = 2
  float* out = blockIdx.z ? dec_raw : tau_raw;
  __shared__ float q[128];
  if (threadIdx.x < 128) q[threadIdx.x] = qs[i0 + threadIdx.x];
  __syncthreads();
  float acc = 0.f;
#pragma unroll 8
  for (int i = 0; i < 128; i++) acc = fmaf(q[i], W[(size_t)(i0 + i) * FD + j], acc);
  atomicAdd(&out[j], acc);
}

// ---------- post: tau_q, s, deco, qact, scalar partials ----------
__global__ void k_post(const float* tau_raw, const float* dec_raw, const float* qs,
                       const float* b_tau, const float* b_dec, const int* tstep,
                       float* s_arr, float* qact, float* scal) {
  int j = blockIdx.x * 256 + threadIdx.x;
  float t = (float)tstep[0];
  float coh = expf(-0.01f * t);
  float tq = (5.f + 45.f * sig(tau_raw[j] + b_tau[j])) / 3.2f;
  s_arr[j] = 0.03125f / tq;                  // dt_q / tau_q, dt_q = 0.1/3.2
  float dec = sig(dec_raw[j] + b_dec[j]);
  qact[j] = qs[j] * dec * coh;
  float tsum = tq, dsum = dec;
  for (int off = 32; off; off >>= 1) {
    tsum += __shfl_down(tsum, off);
    dsum += __shfl_down(dsum, off);
  }
  __shared__ float rt[4], rd[4];
  int w = threadIdx.x >> 6;
  if ((threadIdx.x & 63) == 0) { rt[w] = tsum; rd[w] = dsum; }
  __syncthreads();
  if (threadIdx.x == 0) {
    atomicAdd(&scal[1], rd[0] + rd[1] + rd[2] + rd[3]);
    atomicAdd(&scal[2], rt[0] + rt[1] + rt[2] + rt[3]);
  }
}

// ---------- GEMM + fused h-update epilogue (f32 out) ----------
// Register-staged, single LDS buffer, 2 barriers/K-step.
__global__ __launch_bounds__(256) void k_gemm(
    const __hip_bfloat16* __restrict__ Ah,   // hidden bf16 [BD][FD]
    const __hip_bfloat16* __restrict__ MT,   // [FD][FD]  (B stored [N][K])
    const __hip_bfloat16* __restrict__ Ax,   // inputs bf16 [BD][ID]
    const __hip_bfloat16* __restrict__ WT,   // [FD][ID]
    const float* __restrict__ hidden,        // f32 [BD][FD]
    const float* __restrict__ b_in, const float* __restrict__ s_arr,
    const float* __restrict__ qact,
    float* ent_sum, float* __restrict__ out) {
  __shared__ alignas(16) __hip_bfloat16 As[128][32];
  __shared__ alignas(16) __hip_bfloat16 Bs[128][32];
  __shared__ float red[4];

  const int tid = threadIdx.x;
  const int l = tid & 63, w = tid >> 6;
  const int wr = w >> 1, wc = w & 1;
  const int row0 = blockIdx.x * 128, col0 = blockIdx.y * 128;

  // staging map: 512 chunks (128 rows x 4 col-chunks of 8 bf16)
  const int r0 = tid >> 2,          c0 = (tid & 3) * 8;
  const int r1 = (tid + 256) >> 2,  c1 = ((tid + 256) & 3) * 8;

  v4f acc[4][4];
#pragma unroll
  for (int i = 0; i < 4; i++)
#pragma unroll
    for (int j = 0; j < 4; j++) acc[i][j] = (v4f)0.f;

  v8bf na0, na1, nb0, nb1;

  auto gload = [&](const __hip_bfloat16* A, int lda,
                   const __hip_bfloat16* B, int ldb, int k) {
    na0 = *(const v8bf*)(A + (size_t)(row0 + r0) * lda + k + c0);
    na1 = *(const v8bf*)(A + (size_t)(row0 + r1) * lda + k + c1);
    nb0 = *(const v8bf*)(B + (size_t)(col0 + r0) * ldb + k + c0);
    nb1 = *(const v8bf*)(B + (size_t)(col0 + r1) * ldb + k + c1);
  };
  auto swrite = [&]() {
    *(v8bf*)&As[r0][c0] = na0;
    *(v8bf*)&As[r1][c1] = na1;
    *(v8bf*)&Bs[r0][c0] = nb0;
    *(v8bf*)&Bs[r1][c1] = nb1;
  };
  auto compute = [&]() {
    v8bf a[4], b[4];
#pragma unroll
    for (int mi = 0; mi < 4; mi++)
      a[mi] = *(const v8bf*)&As[wr * 64 + mi * 16 + (l & 15)][(l >> 4) * 8];
#pragma unroll
    for (int ni = 0; ni < 4; ni++)
      b[ni] = *(const v8bf*)&Bs[wc * 64 + ni * 16 + (l & 15)][(l >> 4) * 8];
#pragma unroll
    for (int mi = 0; mi < 4; mi++)
#pragma unroll
      for (int ni = 0; ni < 4; ni++)
        acc[mi][ni] = __builtin_amdgcn_mfma_f32_16x16x32_bf16(a[mi], b[ni], acc[mi][ni], 0, 0, 0);
  };

  // phase 0: ent = hidden @ M   (K = FD)
  gload(Ah, FD, MT, FD, 0);
  swrite();
  for (int kt = 0; kt < FD / 32; kt++) {
    __syncthreads();                                   // tile kt visible
    if (kt + 1 < FD / 32) gload(Ah, FD, MT, FD, (kt + 1) * 32);
    compute();
    __syncthreads();                                   // LDS reads done
    if (kt + 1 < FD / 32) swrite();
  }

  // |ent| partial (acc currently holds ent_rec tile)
  float asum = 0.f;
#pragma unroll
  for (int mi = 0; mi < 4; mi++)
#pragma unroll
    for (int ni = 0; ni < 4; ni++)
#pragma unroll
      for (int e = 0; e < 4; e++) asum += fabsf(acc[mi][ni][e]);

  // phase 1: += inputs @ W_in   (K = ID)
  gload(Ax, ID, WT, ID, 0);
  swrite();
  for (int kt = 0; kt < ID / 32; kt++) {
    __syncthreads();
    if (kt + 1 < ID / 32) gload(Ax, ID, WT, ID, (kt + 1) * 32);
    compute();
    __syncthreads();
    if (kt + 1 < ID / 32) swrite();
  }

  // block-reduce |ent|
  for (int off = 32; off; off >>= 1) asum += __shfl_down(asum, off);
  if (l == 0) red[w] = asum;
  __syncthreads();
  if (tid == 0) atomicAdd(ent_sum, red[0] + red[1] + red[2] + red[3]);

  // fused epilogue: out = h + s*(tanh(g+b)+qact - h)   (f32 stores)
#pragma unroll
  for (int ni = 0; ni < 4; ni++) {
    int gc = col0 + wc * 64 + ni * 16 + (l & 15);
    float bi = b_in[gc], qa = qact[gc], sj = s_arr[gc];
#pragma unroll
    for (int mi = 0; mi < 4; mi++) {
      int gr0 = row0 + wr * 64 + mi * 16 + (l >> 4) * 4;
#pragma unroll
      for (int e = 0; e < 4; e++) {
        int gr = gr0 + e;
        float comb = tanhf(acc[mi][ni][e] + bi) + qa;
        float h = hidden[(size_t)gr * FD + gc];
        out[(size_t)gr * FD + gc] = fmaf(sj, comb - h, h);
      }
    }
  }
}

// ---------- d_amp broadcast: out1[b][c] = pamp[c]  (f32, coalesced) ----------
__global__ void k_damp(const float* __restrict__ pamp, float* __restrict__ out1) {
  int i = blockIdx.x * 256 + threadIdx.x;     // float4 index
  int c = (i * 4) & (FD - 1);
  ((float4*)out1)[i] = *(const float4*)&pamp[c];
}

// ---------- finalize scalars (f32) ----------
__global__ void k_fin(const float* scal, const int* tstep, float* out) {
  if (threadIdx.x == 0) {
    float t = (float)tstep[0];
    float* o = out + (size_t)2 * BD * FD;
    o[0] = expf(-0.01f * t);
    o[1] = scal[0] / (float)((size_t)BD * FD);
    o[2] = scal[1] / (float)FD;
    o[3] = scal[2] / (float)FD;
  }
}

extern "C" void kernel_launch(void* const* d_in, const int* in_sizes, int n_in,
                              void* d_out, int out_size, void* d_ws, size_t ws_size,
                              hipStream_t stream) {
  const float* inputs  = (const float*)d_in[0];
  const float* hidden  = (const float*)d_in[1];
  const float* W_in    = (const float*)d_in[2];
  const float* b_in    = (const float*)d_in[3];
  const float* amp_r   = (const float*)d_in[4];
  const float* amp_i   = (const float*)d_in[5];
  const float* phase   = (const float*)d_in[6];
  const float* primary = (const float*)d_in[7];
  const float* ent_mat = (const float*)d_in[8];
  const float* corr    = (const float*)d_in[9];
  const float* W_tau   = (const float*)d_in[10];
  const float* b_tau   = (const float*)d_in[11];
  const float* W_dec   = (const float*)d_in[12];
  const float* b_dec   = (const float*)d_in[13];
  const int*   tstep   = (const int*)d_in[14];

  char* ws = (char*)d_ws;
  __hip_bfloat16* inputs_bf = (__hip_bfloat16*)(ws + 0);         //  8 MB
  __hip_bfloat16* hidden_bf = (__hip_bfloat16*)(ws + 8388608);   // 16 MB
  __hip_bfloat16* WT        = (__hip_bfloat16*)(ws + 25165824);  //  4 MB
  __hip_bfloat16* MT        = (__hip_bfloat16*)(ws + 29360128);  //  8 MB
  char* sb = ws + 37748736;
  float* scal    = (float*)(sb);          // [0]=ent_sum [1]=dec_sum [2]=tau_sum
  float* qs      = (float*)(sb + 16);
  float* pamp    = (float*)(sb + 16 + 8192);
  float* tau_raw = (float*)(sb + 16 + 2 * 8192);
  float* dec_raw = (float*)(sb + 16 + 3 * 8192);
  float* s_arr   = (float*)(sb + 16 + 4 * 8192);
  float* qact    = (float*)(sb + 16 + 5 * 8192);

  float* out = (float*)d_out;

  hipLaunchKernelGGL(k_init, dim3(8), dim3(256), 0, stream, scal, tau_raw, dec_raw);
  hipLaunchKernelGGL(k_prep_q, dim3(8), dim3(256), 0, stream, amp_r, amp_i, phase, tstep, qs, pamp);
  hipLaunchKernelGGL(k_cast, dim3(4096), dim3(256), 0, stream, inputs, inputs_bf, BD * ID / 4);
  hipLaunchKernelGGL(k_cast, dim3(8192), dim3(256), 0, stream, hidden, hidden_bf, BD * FD / 4);
  hipLaunchKernelGGL(k_tcast, dim3(64, 32), dim3(32, 8), 0, stream,
                     W_in, (const float*)nullptr, (const float*)nullptr, WT, ID, FD, 0);
  hipLaunchKernelGGL(k_tcast, dim3(64, 64), dim3(32, 8), 0, stream,
                     primary, ent_mat, corr, MT, FD, FD, 1);
  hipLaunchKernelGGL(k_matvec, dim3(8, 16, 2), dim3(256), 0, stream, qs, W_tau, W_dec, tau_raw, dec_raw);
  hipLaunchKernelGGL(k_post, dim3(8), dim3(256), 0, stream, tau_raw, dec_raw, qs, b_tau, b_dec, tstep, s_arr, qact, scal);
  hipLaunchKernelGGL(k_gemm, dim3(32, 16), dim3(256), 0, stream,
                     hidden_bf, MT, inputs_bf, WT, hidden, b_in, s_arr, qact,
                     &scal[0], out);
  hipLaunchKernelGGL(k_damp, dim3(8192), dim3(256), 0, stream, pamp, out + (size_t)BD * FD);
  hipLaunchKernelGGL(k_fin, dim3(1), dim3(64), 0, stream, scal, tstep, out);
}

// Round 4
// 150.082 us; speedup vs baseline: 1.0008x; 1.0008x over previous
//
#include <hip/hip_runtime.h>
#include <hip/hip_bf16.h>

#define BD 4096
#define ID 1024
#define FD 2048

typedef __bf16 v8bf __attribute__((ext_vector_type(8)));
typedef float  v4f  __attribute__((ext_vector_type(4)));

struct alignas(8) bf4 { __hip_bfloat16 x, y, z, w; };

__device__ inline __hip_bfloat16 bf(float f) { return __float2bfloat16(f); }
__device__ inline float sig(float x) { return 1.f / (1.f + expf(-x)); }

__device__ inline void gload16(const __hip_bfloat16* g, __hip_bfloat16* l) {
  __builtin_amdgcn_global_load_lds(
      (const __attribute__((address_space(1))) void*)g,
      (__attribute__((address_space(3))) void*)l, 16, 0, 0);
}

// ---------- quantum state prep (+ zero accumulators) ----------
__global__ void k_prep_q(const float* ar, const float* ai, const float* ph,
                         const int* tstep, float* qs, float* pamp,
                         float* scal, float* tau_raw, float* dec_raw) {
  int j = blockIdx.x * 256 + threadIdx.x;
  if (j < 4) scal[j] = 0.f;
  if (j < FD) { tau_raw[j] = 0.f; dec_raw[j] = 0.f; }
  if (j >= FD) return;
  float t = (float)tstep[0];
  float4 a = ((const float4*)ar)[j];
  float4 b = ((const float4*)ai)[j];
  float4 p = ((const float4*)ph)[j];
  float sr = 0.f, si = 0.f, pm = 0.f;
  {
    float c, s, rc, ic;
    c = cosf(p.x + 0.1f * t); s = sinf(p.x + 0.1f * t);
    rc = a.x * c; ic = b.x * s; sr += rc; si += ic; pm += rc * rc + ic * ic;
    c = cosf(p.y + 0.1f * t); s = sinf(p.y + 0.1f * t);
    rc = a.y * c; ic = b.y * s; sr += rc; si += ic; pm += rc * rc + ic * ic;
    c = cosf(p.z + 0.1f * t); s = sinf(p.z + 0.1f * t);
    rc = a.z * c; ic = b.z * s; sr += rc; si += ic; pm += rc * rc + ic * ic;
    c = cosf(p.w + 0.1f * t); s = sinf(p.w + 0.1f * t);
    rc = a.w * c; ic = b.w * s; sr += rc; si += ic; pm += rc * rc + ic * ic;
  }
  qs[j] = sr * expf(-si * si);
  pamp[j] = 0.25f * pm;
}

// ---------- f32 -> bf16 cast: inputs then hidden in one launch ----------
__global__ void k_cast(const float* s1, __hip_bfloat16* d1, int n1,
                       const float* s2, __hip_bfloat16* d2) {
  int i = blockIdx.x * blockDim.x + threadIdx.x;
  const float* src = s1; __hip_bfloat16* dst = d1;
  if (i >= n1) { i -= n1; src = s2; dst = d2; }
  float4 v = ((const float4*)src)[i];
  bf4 o{bf(v.x), bf(v.y), bf(v.z), bf(v.w)};
  ((bf4*)dst)[i] = o;
}

// ---------- transpose + cast (+ optional M = P + E*corr[col]) ----------
// src [R][C] f32 -> dst [C][R] bf16
__global__ void k_tcast(const float* src, const float* src2, const float* corr,
                        __hip_bfloat16* dst, int R, int C, int useM) {
  __shared__ float t[32][33];
  int tx = threadIdx.x, ty = threadIdx.y;   // block (32,8)
  int x = blockIdx.x * 32 + tx;             // src col
  int yb = blockIdx.y * 32;                 // src row base
  float cr = useM ? corr[x] : 0.f;
#pragma unroll
  for (int j = 0; j < 4; j++) {
    int y = yb + ty + j * 8;
    float v = src[(size_t)y * C + x];
    if (useM) v += src2[(size_t)y * C + x] * cr;
    t[ty + j * 8][tx] = v;
  }
  __syncthreads();
#pragma unroll
  for (int j = 0; j < 4; j++) {
    int orow = blockIdx.x * 32 + ty + j * 8;  // = src col
    int ocol = yb + tx;                       // = src row
    dst[(size_t)orow * R + ocol] = bf(t[tx][ty + j * 8]);
  }
}

// ---------- split-K matvec: raw[j] += sum_i qs[i] * W[i][j] ----------
__global__ void k_matvec(const float* qs, const float* Wt, const float* Wd,
                         float* tau_raw, float* dec_raw) {
  int j = blockIdx.x * 256 + threadIdx.x;     // grid.x = 8
  int i0 = blockIdx.y * 128;                  // grid.y = 16
  const float* W = blockIdx.z ? Wd : Wt;      // grid.z = 2
  float* out = blockIdx.z ? dec_raw : tau_raw;
  __shared__ float q[128];
  if (threadIdx.x < 128) q[threadIdx.x] = qs[i0 + threadIdx.x];
  __syncthreads();
  float acc = 0.f;
#pragma unroll 8
  for (int i = 0; i < 128; i++) acc = fmaf(q[i], W[(size_t)(i0 + i) * FD + j], acc);
  atomicAdd(&out[j], acc);
}

// ---------- post: tau_q, s, deco, qact, scalar partials ----------
__global__ void k_post(const float* tau_raw, const float* dec_raw, const float* qs,
                       const float* b_tau, const float* b_dec, const int* tstep,
                       float* s_arr, float* qact, float* scal) {
  int j = blockIdx.x * 256 + threadIdx.x;
  float t = (float)tstep[0];
  float coh = expf(-0.01f * t);
  float tq = (5.f + 45.f * sig(tau_raw[j] + b_tau[j])) / 3.2f;
  s_arr[j] = 0.03125f / tq;                  // dt_q / tau_q, dt_q = 0.1/3.2
  float dec = sig(dec_raw[j] + b_dec[j]);
  qact[j] = qs[j] * dec * coh;
  float tsum = tq, dsum = dec;
  for (int off = 32; off; off >>= 1) {
    tsum += __shfl_down(tsum, off);
    dsum += __shfl_down(dsum, off);
  }
  __shared__ float rt[4], rd[4];
  int w = threadIdx.x >> 6;
  if ((threadIdx.x & 63) == 0) { rt[w] = tsum; rd[w] = dsum; }
  __syncthreads();
  if (threadIdx.x == 0) {
    atomicAdd(&scal[1], rd[0] + rd[1] + rd[2] + rd[3]);
    atomicAdd(&scal[2], rt[0] + rt[1] + rt[2] + rt[3]);
  }
}

// ---------- GEMM + fused h-update epilogue (f32 out) ----------
// m97 structure: global_load_lds width-16, double-buffered LDS, 1 barrier/K-step.
__global__ __launch_bounds__(256) void k_gemm(
    const __hip_bfloat16* __restrict__ Ah,   // hidden bf16 [BD][FD]
    const __hip_bfloat16* __restrict__ MT,   // [FD][FD]  (B stored [N][K])
    const __hip_bfloat16* __restrict__ Ax,   // inputs bf16 [BD][ID]
    const __hip_bfloat16* __restrict__ WT,   // [FD][ID]
    const float* __restrict__ hidden,        // f32 [BD][FD]
    const float* __restrict__ b_in, const float* __restrict__ s_arr,
    const float* __restrict__ qact,
    float* ent_sum, float* __restrict__ out) {
  __shared__ alignas(16) __hip_bfloat16 As[2][128][32];
  __shared__ alignas(16) __hip_bfloat16 Bs[2][128][32];
  __shared__ float red[4];

  const int tid = threadIdx.x;
  const int l = tid & 63, w = tid >> 6;
  const int wr = w >> 1, wc = w & 1;
  const int row0 = blockIdx.x * 128, col0 = blockIdx.y * 128;

  v4f acc[4][4];
#pragma unroll
  for (int i = 0; i < 4; i++)
#pragma unroll
    for (int j = 0; j < 4; j++) acc[i][j] = (v4f)0.f;

  // stage one 128x32 tile pair; wave w owns rows [w*32, w*32+32)
  // chunk = 16 rows x 32 cols = 1KB; lane l -> row l>>2, col (l&3)*8
  auto stage = [&](int buf, const __hip_bfloat16* A, int lda,
                   const __hip_bfloat16* B, int ldb, int k) {
#pragma unroll
    for (int i = 0; i < 2; i++) {
      int rr = w * 32 + i * 16;
      gload16(A + (size_t)(row0 + rr + (l >> 2)) * lda + k + (l & 3) * 8,
              &As[buf][rr][0]);
      gload16(B + (size_t)(col0 + rr + (l >> 2)) * ldb + k + (l & 3) * 8,
              &Bs[buf][rr][0]);
    }
  };
  auto compute = [&](int buf) {
    v8bf a[4], b[4];
#pragma unroll
    for (int mi = 0; mi < 4; mi++)
      a[mi] = *(const v8bf*)&As[buf][wr * 64 + mi * 16 + (l & 15)][(l >> 4) * 8];
#pragma unroll
    for (int ni = 0; ni < 4; ni++)
      b[ni] = *(const v8bf*)&Bs[buf][wc * 64 + ni * 16 + (l & 15)][(l >> 4) * 8];
#pragma unroll
    for (int mi = 0; mi < 4; mi++)
#pragma unroll
      for (int ni = 0; ni < 4; ni++)
        acc[mi][ni] = __builtin_amdgcn_mfma_f32_16x16x32_bf16(a[mi], b[ni], acc[mi][ni], 0, 0, 0);
  };

  // phase 0: ent = hidden @ M   (K = FD)
  stage(0, Ah, FD, MT, FD, 0);
  __syncthreads();
  for (int kt = 0; kt < FD / 32; kt++) {
    if (kt + 1 < FD / 32) stage((kt + 1) & 1, Ah, FD, MT, FD, (kt + 1) * 32);
    compute(kt & 1);
    __syncthreads();
  }

  // |ent| partial (acc currently holds ent_rec tile)
  float asum = 0.f;
#pragma unroll
  for (int mi = 0; mi < 4; mi++)
#pragma unroll
    for (int ni = 0; ni < 4; ni++)
#pragma unroll
      for (int e = 0; e < 4; e++) asum += fabsf(acc[mi][ni][e]);

  // phase 1: += inputs @ W_in   (K = ID)
  stage(0, Ax, ID, WT, ID, 0);
  __syncthreads();
  for (int kt = 0; kt < ID / 32; kt++) {
    if (kt + 1 < ID / 32) stage((kt + 1) & 1, Ax, ID, WT, ID, (kt + 1) * 32);
    compute(kt & 1);
    __syncthreads();
  }

  // block-reduce |ent|
  for (int off = 32; off; off >>= 1) asum += __shfl_down(asum, off);
  if (l == 0) red[w] = asum;
  __syncthreads();
  if (tid == 0) atomicAdd(ent_sum, red[0] + red[1] + red[2] + red[3]);

  // fused epilogue: out = h + s*(tanh(g+b)+qact - h)   (f32 stores)
#pragma unroll
  for (int ni = 0; ni < 4; ni++) {
    int gc = col0 + wc * 64 + ni * 16 + (l & 15);
    float bi = b_in[gc], qa = qact[gc], sj = s_arr[gc];
#pragma unroll
    for (int mi = 0; mi < 4; mi++) {
      int gr0 = row0 + wr * 64 + mi * 16 + (l >> 4) * 4;
#pragma unroll
      for (int e = 0; e < 4; e++) {
        int gr = gr0 + e;
        float comb = tanhf(acc[mi][ni][e] + bi) + qa;
        float h = hidden[(size_t)gr * FD + gc];
        out[(size_t)gr * FD + gc] = fmaf(sj, comb - h, h);
      }
    }
  }
}

// ---------- d_amp broadcast + scalar finalize ----------
__global__ void k_damp(const float* __restrict__ pamp, const float* scal,
                       const int* tstep, float* __restrict__ out1, float* out3) {
  int i = blockIdx.x * 256 + threadIdx.x;     // float4 index
  int c = (i * 4) & (FD - 1);
  ((float4*)out1)[i] = *(const float4*)&pamp[c];
  if (i == 0) {
    float t = (float)tstep[0];
    out3[0] = expf(-0.01f * t);
    out3[1] = scal[0] / (float)((size_t)BD * FD);
    out3[2] = scal[1] / (float)FD;
    out3[3] = scal[2] / (float)FD;
  }
}

extern "C" void kernel_launch(void* const* d_in, const int* in_sizes, int n_in,
                              void* d_out, int out_size, void* d_ws, size_t ws_size,
                              hipStream_t stream) {
  const float* inputs  = (const float*)d_in[0];
  const float* hidden  = (const float*)d_in[1];
  const float* W_in    = (const float*)d_in[2];
  const float* b_in    = (const float*)d_in[3];
  const float* amp_r   = (const float*)d_in[4];
  const float* amp_i   = (const float*)d_in[5];
  const float* phase   = (const float*)d_in[6];
  const float* primary = (const float*)d_in[7];
  const float* ent_mat = (const float*)d_in[8];
  const float* corr    = (const float*)d_in[9];
  const float* W_tau   = (const float*)d_in[10];
  const float* b_tau   = (const float*)d_in[11];
  const float* W_dec   = (const float*)d_in[12];
  const float* b_dec   = (const float*)d_in[13];
  const int*   tstep   = (const int*)d_in[14];

  char* ws = (char*)d_ws;
  __hip_bfloat16* inputs_bf = (__hip_bfloat16*)(ws + 0);         //  8 MB
  __hip_bfloat16* hidden_bf = (__hip_bfloat16*)(ws + 8388608);   // 16 MB
  __hip_bfloat16* WT        = (__hip_bfloat16*)(ws + 25165824);  //  4 MB
  __hip_bfloat16* MT        = (__hip_bfloat16*)(ws + 29360128);  //  8 MB
  char* sb = ws + 37748736;
  float* scal    = (float*)(sb);          // [0]=ent_sum [1]=dec_sum [2]=tau_sum
  float* qs      = (float*)(sb + 16);
  float* pamp    = (float*)(sb + 16 + 8192);
  float* tau_raw = (float*)(sb + 16 + 2 * 8192);
  float* dec_raw = (float*)(sb + 16 + 3 * 8192);
  float* s_arr   = (float*)(sb + 16 + 4 * 8192);
  float* qact    = (float*)(sb + 16 + 5 * 8192);

  float* out = (float*)d_out;

  hipLaunchKernelGGL(k_prep_q, dim3(8), dim3(256), 0, stream,
                     amp_r, amp_i, phase, tstep, qs, pamp, scal, tau_raw, dec_raw);
  hipLaunchKernelGGL(k_cast, dim3(12288), dim3(256), 0, stream,
                     inputs, inputs_bf, BD * ID / 4, hidden, hidden_bf);
  hipLaunchKernelGGL(k_tcast, dim3(64, 32), dim3(32, 8), 0, stream,
                     W_in, (const float*)nullptr, (const float*)nullptr, WT, ID, FD, 0);
  hipLaunchKernelGGL(k_tcast, dim3(64, 64), dim3(32, 8), 0, stream,
                     primary, ent_mat, corr, MT, FD, FD, 1);
  hipLaunchKernelGGL(k_matvec, dim3(8, 16, 2), dim3(256), 0, stream, qs, W_tau, W_dec, tau_raw, dec_raw);
  hipLaunchKernelGGL(k_post, dim3(8), dim3(256), 0, stream, tau_raw, dec_raw, qs, b_tau, b_dec, tstep, s_arr, qact, scal);
  hipLaunchKernelGGL(k_gemm, dim3(32, 16), dim3(256), 0, stream,
                     hidden_bf, MT, inputs_bf, WT, hidden, b_in, s_arr, qact,
                     &scal[0], out);
  hipLaunchKernelGGL(k_damp, dim3(8192), dim3(256), 0, stream,
                     pamp, scal, tstep, out + (size_t)BD * FD, out + (size_t)2 * BD * FD);
}

// Round 5
// 142.939 us; speedup vs baseline: 1.0508x; 1.0500x over previous
//
#include <hip/hip_runtime.h>
#include <hip/hip_bf16.h>

#define BD 4096
#define ID 1024
#define FD 2048

typedef __bf16 v8bf __attribute__((ext_vector_type(8)));
typedef float  v4f  __attribute__((ext_vector_type(4)));

struct alignas(8) bf4 { __hip_bfloat16 x, y, z, w; };

__device__ inline __hip_bfloat16 bf(float f) { return __float2bfloat16(f); }
__device__ inline float sig(float x) { return 1.f / (1.f + expf(-x)); }

__device__ inline void gload16(const __hip_bfloat16* g, __hip_bfloat16* l) {
  __builtin_amdgcn_global_load_lds(
      (const __attribute__((address_space(1))) void*)g,
      (__attribute__((address_space(3))) void*)l, 16, 0, 0);
}

// ---------- quantum state prep (+ zero accumulators) ----------
__global__ void k_prep_q(const float* ar, const float* ai, const float* ph,
                         const int* tstep, float* qs, float* pamp,
                         float* scal, float* tau_raw, float* dec_raw) {
  int j = blockIdx.x * 256 + threadIdx.x;
  if (j < 4) scal[j] = 0.f;
  if (j < FD) { tau_raw[j] = 0.f; dec_raw[j] = 0.f; }
  if (j >= FD) return;
  float t = (float)tstep[0];
  float4 a = ((const float4*)ar)[j];
  float4 b = ((const float4*)ai)[j];
  float4 p = ((const float4*)ph)[j];
  float sr = 0.f, si = 0.f, pm = 0.f;
  {
    float c, s, rc, ic;
    c = cosf(p.x + 0.1f * t); s = sinf(p.x + 0.1f * t);
    rc = a.x * c; ic = b.x * s; sr += rc; si += ic; pm += rc * rc + ic * ic;
    c = cosf(p.y + 0.1f * t); s = sinf(p.y + 0.1f * t);
    rc = a.y * c; ic = b.y * s; sr += rc; si += ic; pm += rc * rc + ic * ic;
    c = cosf(p.z + 0.1f * t); s = sinf(p.z + 0.1f * t);
    rc = a.z * c; ic = b.z * s; sr += rc; si += ic; pm += rc * rc + ic * ic;
    c = cosf(p.w + 0.1f * t); s = sinf(p.w + 0.1f * t);
    rc = a.w * c; ic = b.w * s; sr += rc; si += ic; pm += rc * rc + ic * ic;
  }
  qs[j] = sr * expf(-si * si);
  pamp[j] = 0.25f * pm;
}

// ---------- f32 -> bf16 cast: inputs then hidden in one launch ----------
__global__ void k_cast(const float* s1, __hip_bfloat16* d1, int n1,
                       const float* s2, __hip_bfloat16* d2) {
  int i = blockIdx.x * blockDim.x + threadIdx.x;
  const float* src = s1; __hip_bfloat16* dst = d1;
  if (i >= n1) { i -= n1; src = s2; dst = d2; }
  float4 v = ((const float4*)src)[i];
  bf4 o{bf(v.x), bf(v.y), bf(v.z), bf(v.w)};
  ((bf4*)dst)[i] = o;
}

// ---------- transpose + cast (+ optional M = P + E*corr[col]) ----------
// src [R][C] f32 -> dst [C][R] bf16
__global__ void k_tcast(const float* src, const float* src2, const float* corr,
                        __hip_bfloat16* dst, int R, int C, int useM) {
  __shared__ float t[32][33];
  int tx = threadIdx.x, ty = threadIdx.y;   // block (32,8)
  int x = blockIdx.x * 32 + tx;             // src col
  int yb = blockIdx.y * 32;                 // src row base
  float cr = useM ? corr[x] : 0.f;
#pragma unroll
  for (int j = 0; j < 4; j++) {
    int y = yb + ty + j * 8;
    float v = src[(size_t)y * C + x];
    if (useM) v += src2[(size_t)y * C + x] * cr;
    t[ty + j * 8][tx] = v;
  }
  __syncthreads();
#pragma unroll
  for (int j = 0; j < 4; j++) {
    int orow = blockIdx.x * 32 + ty + j * 8;  // = src col
    int ocol = yb + tx;                       // = src row
    dst[(size_t)orow * R + ocol] = bf(t[tx][ty + j * 8]);
  }
}

// ---------- split-K matvec: raw[j] += sum_i qs[i] * W[i][j] ----------
__global__ void k_matvec(const float* qs, const float* Wt, const float* Wd,
                         float* tau_raw, float* dec_raw) {
  int j = blockIdx.x * 256 + threadIdx.x;     // grid.x = 8
  int i0 = blockIdx.y * 128;                  // grid.y = 16
  const float* W = blockIdx.z ? Wd : Wt;      // grid.z = 2
  float* out = blockIdx.z ? dec_raw : tau_raw;
  __shared__ float q[128];
  if (threadIdx.x < 128) q[threadIdx.x] = qs[i0 + threadIdx.x];
  __syncthreads();
  float acc = 0.f;
#pragma unroll 8
  for (int i = 0; i < 128; i++) acc = fmaf(q[i], W[(size_t)(i0 + i) * FD + j], acc);
  atomicAdd(&out[j], acc);
}

// ---------- post: tau_q, s, deco, qact, scalar partials ----------
__global__ void k_post(const float* tau_raw, const float* dec_raw, const float* qs,
                       const float* b_tau, const float* b_dec, const int* tstep,
                       float* s_arr, float* qact, float* scal) {
  int j = blockIdx.x * 256 + threadIdx.x;
  float t = (float)tstep[0];
  float coh = expf(-0.01f * t);
  float tq = (5.f + 45.f * sig(tau_raw[j] + b_tau[j])) / 3.2f;
  s_arr[j] = 0.03125f / tq;                  // dt_q / tau_q, dt_q = 0.1/3.2
  float dec = sig(dec_raw[j] + b_dec[j]);
  qact[j] = qs[j] * dec * coh;
  float tsum = tq, dsum = dec;
  for (int off = 32; off; off >>= 1) {
    tsum += __shfl_down(tsum, off);
    dsum += __shfl_down(dsum, off);
  }
  __shared__ float rt[4], rd[4];
  int w = threadIdx.x >> 6;
  if ((threadIdx.x & 63) == 0) { rt[w] = tsum; rd[w] = dsum; }
  __syncthreads();
  if (threadIdx.x == 0) {
    atomicAdd(&scal[1], rd[0] + rd[1] + rd[2] + rd[3]);
    atomicAdd(&scal[2], rt[0] + rt[1] + rt[2] + rt[3]);
  }
}

// ---------- GEMM + fused h-update epilogue (f32 out) ----------
// 128x64 tile -> 1024 blocks -> 4 blocks/CU. gload_lds dbuf, 1 barrier/K-step.
__global__ __launch_bounds__(256, 4) void k_gemm(
    const __hip_bfloat16* __restrict__ Ah,   // hidden bf16 [BD][FD]
    const __hip_bfloat16* __restrict__ MT,   // [FD][FD]  (B stored [N][K])
    const __hip_bfloat16* __restrict__ Ax,   // inputs bf16 [BD][ID]
    const __hip_bfloat16* __restrict__ WT,   // [FD][ID]
    const float* __restrict__ b_in, const float* __restrict__ s_arr,
    const float* __restrict__ qact,
    float* ent_sum, float* __restrict__ out) {
  __shared__ alignas(16) __hip_bfloat16 As[2][128][32];
  __shared__ alignas(16) __hip_bfloat16 Bs[2][64][32];
  __shared__ float red[4];

  const int tid = threadIdx.x;
  const int l = tid & 63, w = tid >> 6;
  const int wr = w >> 1, wc = w & 1;     // wave tile: 64 rows x 32 cols
  const int row0 = blockIdx.x * 128, col0 = blockIdx.y * 64;

  v4f acc[4][2];
#pragma unroll
  for (int i = 0; i < 4; i++)
#pragma unroll
    for (int j = 0; j < 2; j++) acc[i][j] = (v4f)0.f;

  // staging: A = 8 chunks (16 rows x 32 cols = 1KB each), wave w -> chunks 2w,2w+1
  //          B = 4 chunks, wave w -> chunk w.  lane l -> row l>>2, col (l&3)*8
  auto stage = [&](int buf, const __hip_bfloat16* A, int lda,
                   const __hip_bfloat16* B, int ldb, int k) {
    gload16(A + (size_t)(row0 + w * 32 + (l >> 2)) * lda + k + (l & 3) * 8,
            &As[buf][w * 32][0]);
    gload16(A + (size_t)(row0 + w * 32 + 16 + (l >> 2)) * lda + k + (l & 3) * 8,
            &As[buf][w * 32 + 16][0]);
    gload16(B + (size_t)(col0 + w * 16 + (l >> 2)) * ldb + k + (l & 3) * 8,
            &Bs[buf][w * 16][0]);
  };
  auto compute = [&](int buf) {
    v8bf a[4], b[2];
#pragma unroll
    for (int mi = 0; mi < 4; mi++)
      a[mi] = *(const v8bf*)&As[buf][wr * 64 + mi * 16 + (l & 15)][(l >> 4) * 8];
#pragma unroll
    for (int ni = 0; ni < 2; ni++)
      b[ni] = *(const v8bf*)&Bs[buf][wc * 32 + ni * 16 + (l & 15)][(l >> 4) * 8];
#pragma unroll
    for (int mi = 0; mi < 4; mi++)
#pragma unroll
      for (int ni = 0; ni < 2; ni++)
        acc[mi][ni] = __builtin_amdgcn_mfma_f32_16x16x32_bf16(a[mi], b[ni], acc[mi][ni], 0, 0, 0);
  };

  // phase 0: ent = hidden @ M   (K = FD)
  stage(0, Ah, FD, MT, FD, 0);
  __syncthreads();
  for (int kt = 0; kt < FD / 32; kt++) {
    if (kt + 1 < FD / 32) stage((kt + 1) & 1, Ah, FD, MT, FD, (kt + 1) * 32);
    compute(kt & 1);
    __syncthreads();
  }

  // |ent| partial (acc currently holds ent_rec tile)
  float asum = 0.f;
#pragma unroll
  for (int mi = 0; mi < 4; mi++)
#pragma unroll
    for (int ni = 0; ni < 2; ni++)
#pragma unroll
      for (int e = 0; e < 4; e++) asum += fabsf(acc[mi][ni][e]);

  // phase 1: += inputs @ W_in   (K = ID)
  stage(0, Ax, ID, WT, ID, 0);
  __syncthreads();
  for (int kt = 0; kt < ID / 32; kt++) {
    if (kt + 1 < ID / 32) stage((kt + 1) & 1, Ax, ID, WT, ID, (kt + 1) * 32);
    compute(kt & 1);
    __syncthreads();
  }

  // block-reduce |ent|
  for (int off = 32; off; off >>= 1) asum += __shfl_down(asum, off);
  if (l == 0) red[w] = asum;
  __syncthreads();
  if (tid == 0) atomicAdd(ent_sum, red[0] + red[1] + red[2] + red[3]);

  // fused epilogue: out = h + s*(tanh(g+b)+qact - h)   (bf16 h, f32 stores)
#pragma unroll
  for (int ni = 0; ni < 2; ni++) {
    int gc = col0 + wc * 32 + ni * 16 + (l & 15);
    float bi = b_in[gc], qa = qact[gc], sj = s_arr[gc];
#pragma unroll
    for (int mi = 0; mi < 4; mi++) {
      int gr0 = row0 + wr * 64 + mi * 16 + (l >> 4) * 4;
#pragma unroll
      for (int e = 0; e < 4; e++) {
        int gr = gr0 + e;
        float comb = tanhf(acc[mi][ni][e] + bi) + qa;
        float h = __bfloat162float(Ah[(size_t)gr * FD + gc]);
        out[(size_t)gr * FD + gc] = fmaf(sj, comb - h, h);
      }
    }
  }
}

// ---------- d_amp broadcast + scalar finalize ----------
__global__ void k_damp(const float* __restrict__ pamp, const float* scal,
                       const int* tstep, float* __restrict__ out1, float* out3) {
  int i = blockIdx.x * 256 + threadIdx.x;     // float4 index
  int c = (i * 4) & (FD - 1);
  ((float4*)out1)[i] = *(const float4*)&pamp[c];
  if (i == 0) {
    float t = (float)tstep[0];
    out3[0] = expf(-0.01f * t);
    out3[1] = scal[0] / (float)((size_t)BD * FD);
    out3[2] = scal[1] / (float)FD;
    out3[3] = scal[2] / (float)FD;
  }
}

extern "C" void kernel_launch(void* const* d_in, const int* in_sizes, int n_in,
                              void* d_out, int out_size, void* d_ws, size_t ws_size,
                              hipStream_t stream) {
  const float* inputs  = (const float*)d_in[0];
  const float* hidden  = (const float*)d_in[1];
  const float* W_in    = (const float*)d_in[2];
  const float* b_in    = (const float*)d_in[3];
  const float* amp_r   = (const float*)d_in[4];
  const float* amp_i   = (const float*)d_in[5];
  const float* phase   = (const float*)d_in[6];
  const float* primary = (const float*)d_in[7];
  const float* ent_mat = (const float*)d_in[8];
  const float* corr    = (const float*)d_in[9];
  const float* W_tau   = (const float*)d_in[10];
  const float* b_tau   = (const float*)d_in[11];
  const float* W_dec   = (const float*)d_in[12];
  const float* b_dec   = (const float*)d_in[13];
  const int*   tstep   = (const int*)d_in[14];

  char* ws = (char*)d_ws;
  __hip_bfloat16* inputs_bf = (__hip_bfloat16*)(ws + 0);         //  8 MB
  __hip_bfloat16* hidden_bf = (__hip_bfloat16*)(ws + 8388608);   // 16 MB
  __hip_bfloat16* WT        = (__hip_bfloat16*)(ws + 25165824);  //  4 MB
  __hip_bfloat16* MT        = (__hip_bfloat16*)(ws + 29360128);  //  8 MB
  char* sb = ws + 37748736;
  float* scal    = (float*)(sb);          // [0]=ent_sum [1]=dec_sum [2]=tau_sum
  float* qs      = (float*)(sb + 16);
  float* pamp    = (float*)(sb + 16 + 8192);
  float* tau_raw = (float*)(sb + 16 + 2 * 8192);
  float* dec_raw = (float*)(sb + 16 + 3 * 8192);
  float* s_arr   = (float*)(sb + 16 + 4 * 8192);
  float* qact    = (float*)(sb + 16 + 5 * 8192);

  float* out = (float*)d_out;

  hipLaunchKernelGGL(k_prep_q, dim3(8), dim3(256), 0, stream,
                     amp_r, amp_i, phase, tstep, qs, pamp, scal, tau_raw, dec_raw);
  hipLaunchKernelGGL(k_cast, dim3(12288), dim3(256), 0, stream,
                     inputs, inputs_bf, BD * ID / 4, hidden, hidden_bf);
  hipLaunchKernelGGL(k_tcast, dim3(64, 32), dim3(32, 8), 0, stream,
                     W_in, (const float*)nullptr, (const float*)nullptr, WT, ID, FD, 0);
  hipLaunchKernelGGL(k_tcast, dim3(64, 64), dim3(32, 8), 0, stream,
                     primary, ent_mat, corr, MT, FD, FD, 1);
  hipLaunchKernelGGL(k_matvec, dim3(8, 16, 2), dim3(256), 0, stream, qs, W_tau, W_dec, tau_raw, dec_raw);
  hipLaunchKernelGGL(k_post, dim3(8), dim3(256), 0, stream, tau_raw, dec_raw, qs, b_tau, b_dec, tstep, s_arr, qact, scal);
  hipLaunchKernelGGL(k_gemm, dim3(32, 32), dim3(256), 0, stream,
                     hidden_bf, MT, inputs_bf, WT, b_in, s_arr, qact,
                     &scal[0], out);
  hipLaunchKernelGGL(k_damp, dim3(8192), dim3(256), 0, stream,
                     pamp, scal, tstep, out + (size_t)BD * FD, out + (size_t)2 * BD * FD);
}

// Round 6
// 142.657 us; speedup vs baseline: 1.0529x; 1.0020x over previous
//
#include <hip/hip_runtime.h>
#include <hip/hip_bf16.h>

#define BD 4096
#define ID 1024
#define FD 2048

typedef __bf16 v8bf __attribute__((ext_vector_type(8)));
typedef float  v4f  __attribute__((ext_vector_type(4)));

struct alignas(8) bf4 { __hip_bfloat16 x, y, z, w; };

__device__ inline __hip_bfloat16 bf(float f) { return __float2bfloat16(f); }
__device__ inline float sig(float x) { return 1.f / (1.f + expf(-x)); }

__device__ inline void gload16(const __hip_bfloat16* g, __hip_bfloat16* l) {
  __builtin_amdgcn_global_load_lds(
      (const __attribute__((address_space(1))) void*)g,
      (__attribute__((address_space(3))) void*)l, 16, 0, 0);
}

// ---------- quantum state prep (+ zero accumulators) ----------
__global__ void k_prep_q(const float* ar, const float* ai, const float* ph,
                         const int* tstep, float* qs, float* pamp,
                         float* scal, float* tau_raw, float* dec_raw) {
  int j = blockIdx.x * 256 + threadIdx.x;
  if (j < 4) scal[j] = 0.f;
  if (j < FD) { tau_raw[j] = 0.f; dec_raw[j] = 0.f; }
  if (j >= FD) return;
  float t = (float)tstep[0];
  float4 a = ((const float4*)ar)[j];
  float4 b = ((const float4*)ai)[j];
  float4 p = ((const float4*)ph)[j];
  float sr = 0.f, si = 0.f, pm = 0.f;
  {
    float c, s, rc, ic;
    c = cosf(p.x + 0.1f * t); s = sinf(p.x + 0.1f * t);
    rc = a.x * c; ic = b.x * s; sr += rc; si += ic; pm += rc * rc + ic * ic;
    c = cosf(p.y + 0.1f * t); s = sinf(p.y + 0.1f * t);
    rc = a.y * c; ic = b.y * s; sr += rc; si += ic; pm += rc * rc + ic * ic;
    c = cosf(p.z + 0.1f * t); s = sinf(p.z + 0.1f * t);
    rc = a.z * c; ic = b.z * s; sr += rc; si += ic; pm += rc * rc + ic * ic;
    c = cosf(p.w + 0.1f * t); s = sinf(p.w + 0.1f * t);
    rc = a.w * c; ic = b.w * s; sr += rc; si += ic; pm += rc * rc + ic * ic;
  }
  qs[j] = sr * expf(-si * si);
  pamp[j] = 0.25f * pm;
}

// ---------- f32 -> bf16 cast: inputs then hidden in one launch ----------
__global__ void k_cast(const float* s1, __hip_bfloat16* d1, int n1,
                       const float* s2, __hip_bfloat16* d2) {
  int i = blockIdx.x * blockDim.x + threadIdx.x;
  const float* src = s1; __hip_bfloat16* dst = d1;
  if (i >= n1) { i -= n1; src = s2; dst = d2; }
  float4 v = ((const float4*)src)[i];
  bf4 o{bf(v.x), bf(v.y), bf(v.z), bf(v.w)};
  ((bf4*)dst)[i] = o;
}

// ---------- transpose + cast (+ optional M = P + E*corr[col]) ----------
// src [R][C] f32 -> dst [C][R] bf16
__global__ void k_tcast(const float* src, const float* src2, const float* corr,
                        __hip_bfloat16* dst, int R, int C, int useM) {
  __shared__ float t[32][33];
  int tx = threadIdx.x, ty = threadIdx.y;   // block (32,8)
  int x = blockIdx.x * 32 + tx;             // src col
  int yb = blockIdx.y * 32;                 // src row base
  float cr = useM ? corr[x] : 0.f;
#pragma unroll
  for (int j = 0; j < 4; j++) {
    int y = yb + ty + j * 8;
    float v = src[(size_t)y * C + x];
    if (useM) v += src2[(size_t)y * C + x] * cr;
    t[ty + j * 8][tx] = v;
  }
  __syncthreads();
#pragma unroll
  for (int j = 0; j < 4; j++) {
    int orow = blockIdx.x * 32 + ty + j * 8;  // = src col
    int ocol = yb + tx;                       // = src row
    dst[(size_t)orow * R + ocol] = bf(t[tx][ty + j * 8]);
  }
}

// ---------- split-K matvec: raw[j] += sum_i qs[i] * W[i][j] ----------
__global__ void k_matvec(const float* qs, const float* Wt, const float* Wd,
                         float* tau_raw, float* dec_raw) {
  int j = blockIdx.x * 256 + threadIdx.x;     // grid.x = 8
  int i0 = blockIdx.y * 128;                  // grid.y = 16
  const float* W = blockIdx.z ? Wd : Wt;      // grid.z = 2
  float* out = blockIdx.z ? dec_raw : tau_raw;
  __shared__ float q[128];
  if (threadIdx.x < 128) q[threadIdx.x] = qs[i0 + threadIdx.x];
  __syncthreads();
  float acc = 0.f;
#pragma unroll 8
  for (int i = 0; i < 128; i++) acc = fmaf(q[i], W[(size_t)(i0 + i) * FD + j], acc);
  atomicAdd(&out[j], acc);
}

// ---------- post: tau_q, s, deco, qact, scalar partials ----------
__global__ void k_post(const float* tau_raw, const float* dec_raw, const float* qs,
                       const float* b_tau, const float* b_dec, const int* tstep,
                       float* s_arr, float* qact, float* scal) {
  int j = blockIdx.x * 256 + threadIdx.x;
  float t = (float)tstep[0];
  float coh = expf(-0.01f * t);
  float tq = (5.f + 45.f * sig(tau_raw[j] + b_tau[j])) / 3.2f;
  s_arr[j] = 0.03125f / tq;                  // dt_q / tau_q, dt_q = 0.1/3.2
  float dec = sig(dec_raw[j] + b_dec[j]);
  qact[j] = qs[j] * dec * coh;
  float tsum = tq, dsum = dec;
  for (int off = 32; off; off >>= 1) {
    tsum += __shfl_down(tsum, off);
    dsum += __shfl_down(dsum, off);
  }
  __shared__ float rt[4], rd[4];
  int w = threadIdx.x >> 6;
  if ((threadIdx.x & 63) == 0) { rt[w] = tsum; rd[w] = dsum; }
  __syncthreads();
  if (threadIdx.x == 0) {
    atomicAdd(&scal[1], rd[0] + rd[1] + rd[2] + rd[3]);
    atomicAdd(&scal[2], rt[0] + rt[1] + rt[2] + rt[3]);
  }
}

// ---------- GEMM + fused h-update epilogue (f32 out) ----------
// 128x64 tile, 4 blocks/CU, gload_lds dbuf, XOR-swizzled LDS (16B blocks):
// LDS block slot blk = cb ^ ((row>>1)&3); applied on the GLOBAL source on the
// write side (rule 21: gload_lds writes linearly) and on the ds_read address.
__global__ __launch_bounds__(256, 4) void k_gemm(
    const __hip_bfloat16* __restrict__ Ah,   // hidden bf16 [BD][FD]
    const __hip_bfloat16* __restrict__ MT,   // [FD][FD]  (B stored [N][K])
    const __hip_bfloat16* __restrict__ Ax,   // inputs bf16 [BD][ID]
    const __hip_bfloat16* __restrict__ WT,   // [FD][ID]
    const float* __restrict__ b_in, const float* __restrict__ s_arr,
    const float* __restrict__ qact,
    float* ent_sum, float* __restrict__ out) {
  __shared__ alignas(16) __hip_bfloat16 As[2][128][32];
  __shared__ alignas(16) __hip_bfloat16 Bs[2][64][32];
  __shared__ float red[4];

  const int tid = threadIdx.x;
  const int l = tid & 63, w = tid >> 6;
  const int wr = w >> 1, wc = w & 1;     // wave tile: 64 rows x 32 cols
  const int row0 = blockIdx.x * 128, col0 = blockIdx.y * 64;

  v4f acc[4][2];
#pragma unroll
  for (int i = 0; i < 4; i++)
#pragma unroll
    for (int j = 0; j < 2; j++) acc[i][j] = (v4f)0.f;

  // write-side swizzle: lane l stages global (row l>>2, colblk (l&3)^((l>>3)&3))
  const int srow = l >> 2;
  const int scol = ((l & 3) ^ ((l >> 3) & 3)) * 8;
  // read-side swizzle: colblk' = (l>>4) ^ ((l>>1)&3)   (row ≡ l&15 mod 16)
  const int rcol = ((l >> 4) ^ ((l >> 1) & 3)) * 8;

  auto stage = [&](int buf, const __hip_bfloat16* A, int lda,
                   const __hip_bfloat16* B, int ldb, int k) {
    gload16(A + (size_t)(row0 + w * 32 + srow) * lda + k + scol,
            &As[buf][w * 32][0]);
    gload16(A + (size_t)(row0 + w * 32 + 16 + srow) * lda + k + scol,
            &As[buf][w * 32 + 16][0]);
    gload16(B + (size_t)(col0 + w * 16 + srow) * ldb + k + scol,
            &Bs[buf][w * 16][0]);
  };
  auto compute = [&](int buf) {
    v8bf a[4], b[2];
#pragma unroll
    for (int mi = 0; mi < 4; mi++)
      a[mi] = *(const v8bf*)&As[buf][wr * 64 + mi * 16 + (l & 15)][rcol];
#pragma unroll
    for (int ni = 0; ni < 2; ni++)
      b[ni] = *(const v8bf*)&Bs[buf][wc * 32 + ni * 16 + (l & 15)][rcol];
#pragma unroll
    for (int mi = 0; mi < 4; mi++)
#pragma unroll
      for (int ni = 0; ni < 2; ni++)
        acc[mi][ni] = __builtin_amdgcn_mfma_f32_16x16x32_bf16(a[mi], b[ni], acc[mi][ni], 0, 0, 0);
  };

  // phase 0: ent = hidden @ M   (K = FD)
  stage(0, Ah, FD, MT, FD, 0);
  __syncthreads();
  for (int kt = 0; kt < FD / 32; kt++) {
    if (kt + 1 < FD / 32) stage((kt + 1) & 1, Ah, FD, MT, FD, (kt + 1) * 32);
    compute(kt & 1);
    __syncthreads();
  }

  // |ent| partial (acc currently holds ent_rec tile)
  float asum = 0.f;
#pragma unroll
  for (int mi = 0; mi < 4; mi++)
#pragma unroll
    for (int ni = 0; ni < 2; ni++)
#pragma unroll
      for (int e = 0; e < 4; e++) asum += fabsf(acc[mi][ni][e]);

  // phase 1: += inputs @ W_in   (K = ID)
  stage(0, Ax, ID, WT, ID, 0);
  __syncthreads();
  for (int kt = 0; kt < ID / 32; kt++) {
    if (kt + 1 < ID / 32) stage((kt + 1) & 1, Ax, ID, WT, ID, (kt + 1) * 32);
    compute(kt & 1);
    __syncthreads();
  }

  // block-reduce |ent|
  for (int off = 32; off; off >>= 1) asum += __shfl_down(asum, off);
  if (l == 0) red[w] = asum;
  __syncthreads();
  if (tid == 0) atomicAdd(ent_sum, red[0] + red[1] + red[2] + red[3]);

  // fused epilogue: out = h + s*(tanh(g+b)+qact - h)   (bf16 h, f32 stores)
#pragma unroll
  for (int ni = 0; ni < 2; ni++) {
    int gc = col0 + wc * 32 + ni * 16 + (l & 15);
    float bi = b_in[gc], qa = qact[gc], sj = s_arr[gc];
#pragma unroll
    for (int mi = 0; mi < 4; mi++) {
      int gr0 = row0 + wr * 64 + mi * 16 + (l >> 4) * 4;
#pragma unroll
      for (int e = 0; e < 4; e++) {
        int gr = gr0 + e;
        float comb = tanhf(acc[mi][ni][e] + bi) + qa;
        float h = __bfloat162float(Ah[(size_t)gr * FD + gc]);
        out[(size_t)gr * FD + gc] = fmaf(sj, comb - h, h);
      }
    }
  }
}

// ---------- d_amp broadcast + scalar finalize ----------
__global__ void k_damp(const float* __restrict__ pamp, const float* scal,
                       const int* tstep, float* __restrict__ out1, float* out3) {
  int i = blockIdx.x * 256 + threadIdx.x;     // float4 index
  int c = (i * 4) & (FD - 1);
  ((float4*)out1)[i] = *(const float4*)&pamp[c];
  if (i == 0) {
    float t = (float)tstep[0];
    out3[0] = expf(-0.01f * t);
    out3[1] = scal[0] / (float)((size_t)BD * FD);
    out3[2] = scal[1] / (float)FD;
    out3[3] = scal[2] / (float)FD;
  }
}

extern "C" void kernel_launch(void* const* d_in, const int* in_sizes, int n_in,
                              void* d_out, int out_size, void* d_ws, size_t ws_size,
                              hipStream_t stream) {
  const float* inputs  = (const float*)d_in[0];
  const float* hidden  = (const float*)d_in[1];
  const float* W_in    = (const float*)d_in[2];
  const float* b_in    = (const float*)d_in[3];
  const float* amp_r   = (const float*)d_in[4];
  const float* amp_i   = (const float*)d_in[5];
  const float* phase   = (const float*)d_in[6];
  const float* primary = (const float*)d_in[7];
  const float* ent_mat = (const float*)d_in[8];
  const float* corr    = (const float*)d_in[9];
  const float* W_tau   = (const float*)d_in[10];
  const float* b_tau   = (const float*)d_in[11];
  const float* W_dec   = (const float*)d_in[12];
  const float* b_dec   = (const float*)d_in[13];
  const int*   tstep   = (const int*)d_in[14];

  char* ws = (char*)d_ws;
  __hip_bfloat16* inputs_bf = (__hip_bfloat16*)(ws + 0);         //  8 MB
  __hip_bfloat16* hidden_bf = (__hip_bfloat16*)(ws + 8388608);   // 16 MB
  __hip_bfloat16* WT        = (__hip_bfloat16*)(ws + 25165824);  //  4 MB
  __hip_bfloat16* MT        = (__hip_bfloat16*)(ws + 29360128);  //  8 MB
  char* sb = ws + 37748736;
  float* scal    = (float*)(sb);          // [0]=ent_sum [1]=dec_sum [2]=tau_sum
  float* qs      = (float*)(sb + 16);
  float* pamp    = (float*)(sb + 16 + 8192);
  float* tau_raw = (float*)(sb + 16 + 2 * 8192);
  float* dec_raw = (float*)(sb + 16 + 3 * 8192);
  float* s_arr   = (float*)(sb + 16 + 4 * 8192);
  float* qact    = (float*)(sb + 16 + 5 * 8192);

  float* out = (float*)d_out;

  hipLaunchKernelGGL(k_prep_q, dim3(8), dim3(256), 0, stream,
                     amp_r, amp_i, phase, tstep, qs, pamp, scal, tau_raw, dec_raw);
  hipLaunchKernelGGL(k_cast, dim3(12288), dim3(256), 0, stream,
                     inputs, inputs_bf, BD * ID / 4, hidden, hidden_bf);
  hipLaunchKernelGGL(k_tcast, dim3(64, 32), dim3(32, 8), 0, stream,
                     W_in, (const float*)nullptr, (const float*)nullptr, WT, ID, FD, 0);
  hipLaunchKernelGGL(k_tcast, dim3(64, 64), dim3(32, 8), 0, stream,
                     primary, ent_mat, corr, MT, FD, FD, 1);
  hipLaunchKernelGGL(k_matvec, dim3(8, 16, 2), dim3(256), 0, stream, qs, W_tau, W_dec, tau_raw, dec_raw);
  hipLaunchKernelGGL(k_post, dim3(8), dim3(256), 0, stream, tau_raw, dec_raw, qs, b_tau, b_dec, tstep, s_arr, qact, scal);
  hipLaunchKernelGGL(k_gemm, dim3(32, 32), dim3(256), 0, stream,
                     hidden_bf, MT, inputs_bf, WT, b_in, s_arr, qact,
                     &scal[0], out);
  hipLaunchKernelGGL(k_damp, dim3(8192), dim3(256), 0, stream,
                     pamp, scal, tstep, out + (size_t)BD * FD, out + (size_t)2 * BD * FD);
}